// Round 1
// baseline (58424.139 us; speedup 1.0000x reference)
//
#include <hip/hip_runtime.h>

#define V  32000
#define E  256
#define H  512
#define BB 32
#define TS 512
#define TT 128
#define NT 127   // decoder steps = TT-1

// ---- workspace layout (float words) ----
#define OFF_WBF  0ull            // ushort[32000*512] transposed [v][k] -> 8,192,000 float words
#define OFF_WT   8192000ull      // float[32000*512]  (Wout^T, [v][k], fp32 for refine)
#define OFF_PT   24576000ull     // top2 partials: 250*32*2*(val,idx) = 32000 words
#define OFF_H0   24608000ull     // 2 * 32*512 ping-pong
#define OFF_H1   24640768ull
#define OFF_TOK  24673536ull     // 32 ints
#define OFF_CNT  24673568ull     // 1 int (logits last-block counter)
// total ~24.67M words = 98.7 MB.  pre0 (512*32*512 f32 = 33.5MB) lives in d_out.

typedef unsigned short us8 __attribute__((ext_vector_type(8)));

// grid-barrier counters live in module static memory (NOT ws -> no layout growth).
// 2 barriers (enc, dec) x 8 sub-counters x 16-int stride (64B lines).
__device__ int g_bar[256];

__device__ inline unsigned short f2bf(float f){
  unsigned int x = __float_as_uint(f);
  unsigned int r = x + 0x7fffu + ((x >> 16) & 1u);
  return (unsigned short)(r >> 16);
}
__device__ inline float bf2f(unsigned short u){
  return __uint_as_float(((unsigned int)u) << 16);
}

// device-scope grid barrier: monotonic epoch target, 8-way split arrive counters.
// release: __threadfence() (wbL2) before arrive; acquire: __threadfence() (invL2) after.
// Co-residency of ALL blocks is guaranteed by grid sizing (see launch comments).
#define BARSTRIDE 16
__device__ __forceinline__ void gridbar(int* base, int target){
  __syncthreads();
  if (threadIdx.x == 0){
    __threadfence();
    atomicAdd(base + (blockIdx.x & 7)*BARSTRIDE, 1);
    for (;;){
      int s = 0;
      #pragma unroll
      for (int q = 0; q < 8; q++)
        s += __hip_atomic_load(base + q*BARSTRIDE, __ATOMIC_RELAXED, __HIP_MEMORY_SCOPE_AGENT);
      if (s >= target) break;
      __builtin_amdgcn_s_sleep(2);
    }
    __threadfence();
  }
  __syncthreads();
}

// merge candidate (o1,oi1,o2,oi2) into running top-2 (v1,i1,v2,i2); ties -> lower idx
__device__ inline void top2_merge(float& v1,int& i1,float& v2,int& i2,
                                  float o1,int oi1,float o2,int oi2){
  if (o1 > v1 || (o1 == v1 && oi1 < i1)) {
    float nv2; int ni2;
    if (v1 > o2 || (v1 == o2 && i1 < oi2)) { nv2 = v1; ni2 = i1; }
    else { nv2 = o2; ni2 = oi2; }
    v1 = o1; i1 = oi1; v2 = nv2; i2 = ni2;
  } else if (o1 > v2 || (o1 == v2 && oi1 < i2)) {
    v2 = o1; i2 = oi1;
  }
}

// ---------------- init: zero hidden ping-pongs, seed tokens, zero counters ----
__global__ void k_init(float* ws, const int* tgt){
  int gid = blockIdx.x*256 + threadIdx.x;
  float* h0 = ws + OFF_H0; float* h1 = ws + OFF_H1;
  if (gid < 2*BB*H){ h0[gid] = 0.f; h1[gid] = 0.f; }
  if (gid < BB) ((int*)(ws+OFF_TOK))[gid] = tgt[gid*TT + 0];
  if (gid == 0) ((int*)(ws+OFF_CNT))[0] = 0;
  if (gid < 256) g_bar[gid] = 0;
}

// ------------- Wout prep: TRANSPOSED bf16 [v][k] + fp32 transpose [v][k] -------
__global__ void k_wprep(float* ws, const float* wout){
  int tw = blockIdx.x; int k0 = (tw / 500) * 64; int v0 = (tw % 500) * 64;
  __shared__ float tile[64][65];
  unsigned short* wbfT = (unsigned short*)(ws + OFF_WBF);
  float* wt = ws + OFF_WT;
  for (int i = threadIdx.x; i < 64*64; i += 256){
    int kk = i >> 6, vv = i & 63;
    tile[kk][vv] = wout[(size_t)(k0+kk)*V + v0 + vv];
  }
  __syncthreads();
  for (int i = threadIdx.x; i < 64*64; i += 256){
    int vv = i >> 6, kk = i & 63;
    float val = tile[kk][vv];
    wt  [(size_t)(v0+vv)*H + k0 + kk] = val;
    wbfT[(size_t)(v0+vv)*H + k0 + kk] = f2bf(val);
  }
}

// ------------- pre0[t][b][j] = b0[j] + emb_enc[src[b][t]] @ Wih0 -------------
__global__ void k_pre0(float* pre0, const int* src, const float* emb,
                       const float* Wih0, const float* b0){
  int t = blockIdx.x >> 2; int cb = blockIdx.x & 3;
  __shared__ int sidx[32];
  __shared__ float sA[32][257];
  int tid = threadIdx.x;
  if (tid < 32) sidx[tid] = src[tid*TS + t];
  __syncthreads();
  for (int i = tid; i < 32*E; i += 256){
    int bb = i >> 8, e = i & 255;
    sA[bb][e] = emb[(size_t)sidx[bb]*E + e];
  }
  __syncthreads();
  int c = tid & 127, rh = tid >> 7;
  int j = cb*128 + c;
  float bj = b0[j];
  float acc[16];
  #pragma unroll
  for (int i=0;i<16;i++) acc[i] = bj;
  for (int k=0;k<E;k++){
    float w = Wih0[(size_t)k*H + j];
    #pragma unroll
    for (int i=0;i<16;i++) acc[i] += sA[rh*16+i][k]*w;
  }
  #pragma unroll
  for (int i=0;i<16;i++){
    int b = rh*16 + i;
    pre0[((size_t)t*BB + b)*H + j] = acc[i];
  }
}

// ------------- PERSISTENT encoder: 513 staggered steps, 1 grid barrier each ---
// grid = 192 blocks x 256 thr (<= 256 CUs, 25.6KB LDS -> all co-resident).
// blocks 0..63: layer0 computes h0_tau; blocks 64..191: layer1 computes h1_{tau-1}.
__global__ __launch_bounds__(256,1) void k_encp(
    float* __restrict__ ws, const float* __restrict__ pre0,
    const float* __restrict__ Whh0,
    const float* __restrict__ Wih1, const float* __restrict__ Whh1,
    const float* __restrict__ b1)
{
  float* h0 = ws + OFF_H0; float* h1 = ws + OFF_H1;
  const int wg = blockIdx.x; const int tid = threadIdx.x;
  __shared__ float sh[4*513];
  __shared__ float s0[4*513];
  __shared__ float s1[4*513];
  __shared__ float sp[256];
  int ep = 0;
  for (int tau = 0; tau <= TS; ++tau){
    if (wg < 64){
      if (tau < TS){
        int rb = wg >> 3, cb = wg & 7;
        const float* hprev = h0 + ((tau+1)&1)*BB*H;
        for (int i=tid;i<4*H;i+=256){ int rr=i>>9, k=i&511; sh[rr*513+k]=hprev[(rb*4+rr)*H+k]; }
        __syncthreads();
        int c = tid & 63, rsub = tid >> 6;
        int r = rb*4 + rsub, j = cb*64 + c;
        const float* w = Whh0 + j;
        float a0=0,a1=0,a2=0,a3=0;
        for (int k=0;k<H;k+=4){
          a0 += sh[rsub*513+k+0]*w[(size_t)(k+0)*H];
          a1 += sh[rsub*513+k+1]*w[(size_t)(k+1)*H];
          a2 += sh[rsub*513+k+2]*w[(size_t)(k+2)*H];
          a3 += sh[rsub*513+k+3]*w[(size_t)(k+3)*H];
        }
        float acc = pre0[((size_t)tau*BB + r)*H + j] + ((a0+a1)+(a2+a3));
        h0[(tau&1)*BB*H + r*H + j] = tanhf(acc);
      }
    } else {
      if (tau >= 1){
        int w2 = wg - 64;
        int rb = w2 >> 4, cb = w2 & 15;
        const float* h0t = h0 + ((tau+1)&1)*BB*H;  // h0_{tau-1}
        const float* h1p = h1 + (tau&1)*BB*H;      // h1_{tau-2}
        for (int i=tid;i<4*H;i+=256){
          int rr=i>>9, k=i&511;
          s0[rr*513+k] = h0t[(rb*4+rr)*H+k];
          s1[rr*513+k] = h1p[(rb*4+rr)*H+k];
        }
        __syncthreads();
        int kh = tid >> 7, q = tid & 127;
        int c = q & 31, rsub = q >> 5;
        int r = rb*4 + rsub, j = cb*32 + c;
        const float* W = kh ? (Whh1 + j) : (Wih1 + j);
        const float* shp = kh ? s1 : s0;
        float a0=0,a1=0,a2=0,a3=0;
        for (int k=0;k<H;k+=4){
          a0 += shp[rsub*513+k+0]*W[(size_t)(k+0)*H];
          a1 += shp[rsub*513+k+1]*W[(size_t)(k+1)*H];
          a2 += shp[rsub*513+k+2]*W[(size_t)(k+2)*H];
          a3 += shp[rsub*513+k+3]*W[(size_t)(k+3)*H];
        }
        sp[tid] = ((a0+a1)+(a2+a3));
        __syncthreads();
        if (kh == 0){
          float v = sp[q] + sp[128+q] + b1[j];
          h1[((tau+1)&1)*BB*H + r*H + j] = tanhf(v);
        }
      }
    }
    if (tau < TS){ ++ep; gridbar(g_bar, ep*192); }
  }
}

// ------------- PERSISTENT decoder: 127 steps x {cellA | cellB | logits+select} --
// grid = 500 blocks x 256 thr. LDS union ~50.4KB + launch_bounds(256,2)
// -> >=2 blocks/CU -> 512 slots >= 500: all co-resident.
__global__ __launch_bounds__(256,2) void k_decp(
    float* __restrict__ ws, float* __restrict__ out,
    const float* __restrict__ embd,
    const float* __restrict__ Wih0, const float* __restrict__ Whh0, const float* __restrict__ b0,
    const float* __restrict__ Wih1, const float* __restrict__ Whh1, const float* __restrict__ b1,
    const float* __restrict__ bout, const int* __restrict__ tgt, const int* __restrict__ tf)
{
  float* h0 = ws + OFF_H0; float* h1 = ws + OFF_H1;
  const unsigned short* wbfT = (const unsigned short*)(ws + OFF_WBF);
  const float* wt = ws + OFF_WT;
  float* pt = ws + OFF_PT;
  int* tok = (int*)(ws + OFF_TOK);
  int* cnt = (int*)(ws + OFF_CNT);
  const int blk = blockIdx.x; const int tid = threadIdx.x;
  int* bar = g_bar + 128;

  // LDS union: phaseA 3084 f | phaseB 4360 f | phaseL 12384 f (Lh 16x516, sv/si 16x129)
  __shared__ __align__(16) float smem[12384];
  __shared__ int lastflag;
  __shared__ int candn[32];
  __shared__ int candj[32][6];

  int ep = 0;
  for (int t = 0; t < NT; ++t){
    // ---------- phase A: layer0 cell (blocks 0..63) ----------
    if (blk < 64){
      int rb = blk >> 3, cb = blk & 7;
      int*   stok = (int*)smem;            // [4]
      float* sx   = smem + 4;              // [4][257]
      float* shh  = smem + 4 + 4*257;      // [4][513]
      if (tid < 4) stok[tid] = tok[rb*4 + tid];
      __syncthreads();
      for (int i=tid;i<4*E;i+=256){ int rr=i>>8, e=i&255; sx[rr*257+e] = embd[(size_t)stok[rr]*E + e]; }
      const float* hprev = h0 + ((t+1)&1)*BB*H;
      for (int i=tid;i<4*H;i+=256){ int rr=i>>9, k=i&511; shh[rr*513+k] = hprev[(rb*4+rr)*H + k]; }
      __syncthreads();
      int c = tid & 63, rsub = tid >> 6;
      int r = rb*4 + rsub, j = cb*64 + c;
      float a0=0,a1=0,a2=0,a3=0;
      for (int k=0;k<E;k+=4){
        a0 += sx[rsub*257+k+0]*Wih0[(size_t)(k+0)*H + j];
        a1 += sx[rsub*257+k+1]*Wih0[(size_t)(k+1)*H + j];
        a2 += sx[rsub*257+k+2]*Wih0[(size_t)(k+2)*H + j];
        a3 += sx[rsub*257+k+3]*Wih0[(size_t)(k+3)*H + j];
      }
      for (int k=0;k<H;k+=4){
        a0 += shh[rsub*513+k+0]*Whh0[(size_t)(k+0)*H + j];
        a1 += shh[rsub*513+k+1]*Whh0[(size_t)(k+1)*H + j];
        a2 += shh[rsub*513+k+2]*Whh0[(size_t)(k+2)*H + j];
        a3 += shh[rsub*513+k+3]*Whh0[(size_t)(k+3)*H + j];
      }
      h0[(t&1)*BB*H + r*H + j] = tanhf(b0[j] + ((a0+a1)+(a2+a3)));
    }
    ++ep; gridbar(bar, ep*500);

    // ---------- phase B: layer1 cell (blocks 0..127) ----------
    if (blk < 128){
      int rb = blk >> 4, cb = blk & 15;
      float* s0 = smem;                    // [4][513]
      float* s1 = smem + 2052;             // [4][513]
      float* sp = smem + 4104;             // [256]
      const float* h0c = h0 + (t&1)*BB*H;
      const float* h1p = h1 + ((t+1)&1)*BB*H;
      for (int i=tid;i<4*H;i+=256){
        int rr=i>>9, k=i&511;
        s0[rr*513+k] = h0c[(rb*4+rr)*H+k];
        s1[rr*513+k] = h1p[(rb*4+rr)*H+k];
      }
      __syncthreads();
      int kh = tid >> 7, q = tid & 127;
      int c = q & 31, rsub = q >> 5;
      int r = rb*4 + rsub, j = cb*32 + c;
      const float* W = kh ? (Whh1 + j) : (Wih1 + j);
      const float* shp = kh ? s1 : s0;
      float a0=0,a1=0,a2=0,a3=0;
      for (int k=0;k<H;k+=4){
        a0 += shp[rsub*513+k+0]*W[(size_t)(k+0)*H];
        a1 += shp[rsub*513+k+1]*W[(size_t)(k+1)*H];
        a2 += shp[rsub*513+k+2]*W[(size_t)(k+2)*H];
        a3 += shp[rsub*513+k+3]*W[(size_t)(k+3)*H];
      }
      sp[tid] = ((a0+a1)+(a2+a3));
      __syncthreads();
      if (kh == 0){
        float v = sp[q] + sp[128+q] + b1[j];
        h1[(t&1)*BB*H + r*H + j] = tanhf(v);
      }
    }
    ++ep; gridbar(bar, ep*500);

    // ---------- phase L: logits (all 500 blocks) + top2 + last-block select ----
    {
      int rb = blk / 250, cb = blk % 250;
      float* Lh  = smem;                       // 16 rows, stride 516
      float* sv  = smem + 16*516;              // [16][129]
      int*   si_ = (int*)(smem + 16*516 + 16*129);
      const float* h1c = h1 + (t&1)*BB*H;
      for (int i=tid;i<16*H;i+=256){ int rr=i>>9, k=i&511; Lh[rr*516+k] = h1c[(rb*16+rr)*H + k]; }
      __syncthreads();
      int c = tid & 127, rh = tid >> 7;
      int j = cb*128 + c;
      float bj = bout[j];
      float acc[8];
      #pragma unroll
      for (int i=0;i<8;i++) acc[i] = bj;
      const unsigned short* wr = wbfT + (size_t)j*H;
      for (int k=0;k<H;k+=16){
        us8 wa = *(const us8*)(wr + k);
        us8 wb = *(const us8*)(wr + k + 8);
        float wf[16];
        #pragma unroll
        for (int q=0;q<8;q++) wf[q]   = bf2f(wa[q]);
        #pragma unroll
        for (int q=0;q<8;q++) wf[8+q] = bf2f(wb[q]);
        #pragma unroll
        for (int i=0;i<8;i++){
          const float4* hp = (const float4*)(Lh + (rh*8+i)*516 + k);
          float4 hA = hp[0], hB = hp[1], hC = hp[2], hD = hp[3];
          float s = acc[i];
          s += hA.x*wf[0];  s += hA.y*wf[1];  s += hA.z*wf[2];  s += hA.w*wf[3];
          s += hB.x*wf[4];  s += hB.y*wf[5];  s += hB.z*wf[6];  s += hB.w*wf[7];
          s += hC.x*wf[8];  s += hC.y*wf[9];  s += hC.z*wf[10]; s += hC.w*wf[11];
          s += hD.x*wf[12]; s += hD.y*wf[13]; s += hD.z*wf[14]; s += hD.w*wf[15];
          acc[i] = s;
        }
      }
      #pragma unroll
      for (int i=0;i<8;i++){
        int b = rb*16 + rh*8 + i;
        out[((size_t)b*NT + t)*V + j] = acc[i];
      }
      // per-(row, colblock) top-2
      #pragma unroll
      for (int i=0;i<8;i++){ sv[(rh*8+i)*129 + c] = acc[i]; si_[(rh*8+i)*129 + c] = j; }
      __syncthreads();
      int row = tid >> 4, l16 = tid & 15;
      float v1=-1e30f, v2=-1e30f; int i1=-1, i2=-1;
      for (int s=0;s<8;s++){
        float v = sv[row*129 + l16 + 16*s]; int ix = si_[row*129 + l16 + 16*s];
        top2_merge(v1,i1,v2,i2, v,ix,-1e30f,-1);
      }
      for (int off=8; off>=1; off>>=1){
        float o1 = __shfl_xor(v1, off, 16); int oi1 = __shfl_xor(i1, off, 16);
        float o2 = __shfl_xor(v2, off, 16); int oi2 = __shfl_xor(i2, off, 16);
        top2_merge(v1,i1,v2,i2, o1,oi1,o2,oi2);
      }
      if (l16 == 0){
        int b = rb*16 + row;
        size_t base = ((size_t)cb*32 + b)*4;
        pt[base+0] = v1; ((int*)pt)[base+1] = i1;
        pt[base+2] = v2; ((int*)pt)[base+3] = i2;
      }
      __threadfence();
      __syncthreads();
      if (tid == 0){
        int old = atomicAdd(cnt, 1);
        lastflag = (old == 499);
      }
      __syncthreads();
      if (lastflag){
        __threadfence();
        // ---- select phase (one WG): global max, candidates within delta, fp32 refine
        int b = tid >> 3, l = tid & 7;
        float gm = -1e30f;
        for (int cc=l; cc<250; cc+=8) gm = fmaxf(gm, pt[((size_t)cc*32 + b)*4]);
        for (int off=4; off>=1; off>>=1) gm = fmaxf(gm, __shfl_xor(gm, off, 8));
        if (l == 0) candn[b] = 0;
        __syncthreads();
        float thr = gm - 0.02f;
        for (int cc=l; cc<250; cc+=8){
          #pragma unroll
          for (int s=0;s<2;s++){
            size_t base = ((size_t)cc*32 + b)*4 + s*2;
            float v = pt[base];
            if (v >= thr){
              int slot = atomicAdd(&candn[b], 1);
              if (slot < 6) candj[b][slot] = ((int*)pt)[base+1];
            }
          }
        }
        __syncthreads();
        int n = candn[b]; if (n > 6) n = 6;
        int besti;
        if (n == 1){
          besti = candj[b][0];
        } else {
          float bestv = -1e30f; besti = 0x7fffffff;
          for (int s=0;s<n;s++){
            int jj = candj[b][s];
            const float* wrow = wt + (size_t)jj*H;
            const float* hr = h1c + b*H;
            float p = 0.f;
            for (int kk=l*64; kk<l*64+64; kk++) p += hr[kk]*wrow[kk];
            for (int off=4; off>=1; off>>=1) p += __shfl_xor(p, off, 8);
            p += bout[jj];
            if (p > bestv || (p == bestv && jj < besti)){ bestv = p; besti = jj; }
          }
        }
        if (l == 0) tok[b] = (tf[t] > 0) ? tgt[b*TT + t + 1] : besti;
        if (tid == 0) *cnt = 0;
      }
    }
    ++ep; gridbar(bar, ep*500);
  }
}

extern "C" void kernel_launch(void* const* d_in, const int* in_sizes, int n_in,
                              void* d_out, int out_size, void* d_ws, size_t ws_size,
                              hipStream_t stream) {
  (void)in_sizes; (void)n_in; (void)out_size; (void)ws_size;
  const int*   src     = (const int*)  d_in[0];
  const int*   tgt     = (const int*)  d_in[1];
  const int*   tf      = (const int*)  d_in[2];
  const float* emb_enc = (const float*)d_in[3];
  const float* emb_dec = (const float*)d_in[4];
  const float* eW0     = (const float*)d_in[5];
  const float* eU0     = (const float*)d_in[6];
  const float* eb0     = (const float*)d_in[7];
  const float* eW1     = (const float*)d_in[8];
  const float* eU1     = (const float*)d_in[9];
  const float* eb1     = (const float*)d_in[10];
  const float* dW0     = (const float*)d_in[11];
  const float* dU0     = (const float*)d_in[12];
  const float* db0     = (const float*)d_in[13];
  const float* dW1     = (const float*)d_in[14];
  const float* dU1     = (const float*)d_in[15];
  const float* db1     = (const float*)d_in[16];
  const float* Wout    = (const float*)d_in[17];
  const float* bout    = (const float*)d_in[18];
  float* out = (float*)d_out;
  float* ws  = (float*)d_ws;
  float* pre0 = out;  // scratch alias: fully consumed before decoder writes logits

  k_init <<<128, 256, 0, stream>>>(ws, tgt);
  k_wprep<<<4000,256, 0, stream>>>(ws, Wout);
  k_pre0 <<<2048,256, 0, stream>>>(pre0, src, emb_enc, eW0, eb0);
  // persistent encoder: 192 blocks (all co-resident on 256 CUs)
  k_encp <<<192, 256, 0, stream>>>(ws, pre0, eU0, eW1, eU1, eb1);
  // persistent decoder: 500 blocks (>=2/CU via launch_bounds + 50.4KB LDS)
  k_decp <<<500, 256, 0, stream>>>(ws, out, emb_dec, dW0, dU0, db0,
                                   dW1, dU1, db1, bout, tgt, tf);
}